// Round 2
// baseline (20040.126 us; speedup 1.0000x reference)
//
#include <hip/hip_runtime.h>

typedef unsigned short ushort_t;
typedef unsigned int uint32;

typedef short bf16x8 __attribute__((ext_vector_type(8)));
typedef float f32x4 __attribute__((ext_vector_type(4)));

#define HH 1024
#define BB 32
#define U1 257
#define VV 10001
#define MM (U1*BB)   /* 8224 */
#define KK 1024

__device__ __forceinline__ ushort_t f2bf(float f){
    union { float f; uint32 i; } c; c.f = f;
    uint32 u = c.i;
    uint32 r = (u + 0x7fffu + ((u >> 16) & 1u)) >> 16;  // RNE
    return (ushort_t)r;
}

__global__ __launch_bounds__(256) void k_cast(const float* __restrict__ src,
                                              ushort_t* __restrict__ dst, int n){
    int i = blockIdx.x*256 + threadIdx.x;
    int stride = gridDim.x*256;
    for (; i < n; i += stride) dst[i] = f2bf(src[i]);
}

// x0[(t*32+b)*H + k] = bf16(embed[token(t,b)*H + k]); token = start for t=0 else y[b][t-1]
__global__ __launch_bounds__(256) void k_embed(const int* __restrict__ y,
                                               const float* __restrict__ embed,
                                               ushort_t* __restrict__ x0){
    int i = blockIdx.x*256 + threadIdx.x;
    int stride = gridDim.x*256;
    const int n = MM*HH;
    for (; i < n; i += stride){
        int m = i >> 10, k = i & 1023;
        int t = m >> 5, b = m & 31;
        int tok = (t == 0) ? (VV-1) : y[b*256 + (t-1)];
        x0[i] = f2bf(embed[(size_t)tok*HH + k]);
    }
}

// hT[k*32+b] = init[k]   (32768 threads exactly)
__global__ __launch_bounds__(256) void k_init_hT(const float* __restrict__ init,
                                                 float* __restrict__ hT){
    int i = blockIdx.x*256 + threadIdx.x;
    hT[i] = init[i >> 5];
}

// One GRU step for one layer: gh = h_prev @ Whh^T per output j, then gate math.
// Thread (b fast, j slow): j = tid>>5, b = tid&31.  h_prev in [k][b] fp32 (coalesced).
__global__ __launch_bounds__(256) void k_gru_step(
    const ushort_t* __restrict__ Whh,  // layer base, [3072][1024] bf16
    const float* __restrict__ bhh,     // [3072]
    const float* __restrict__ gi,      // this step: [32][3072] fp32 (includes bih)
    const float* __restrict__ hpT,     // [1024][32] fp32
    float* __restrict__ hnT,           // [1024][32] fp32
    ushort_t* __restrict__ hout)       // [32][1024] bf16 (for later GEMMs)
{
    int tid = blockIdx.x*256 + threadIdx.x;
    int j = tid >> 5, b = tid & 31;
    const ushort_t* wr = Whh + (size_t)j*HH;
    const ushort_t* wz = wr + (size_t)HH*HH;
    const ushort_t* wn = wz + (size_t)HH*HH;
    float ar = 0.f, az = 0.f, an = 0.f;
    #pragma unroll 4
    for (int k8 = 0; k8 < HH; k8 += 8){
        float hv[8];
        #pragma unroll
        for (int i = 0; i < 8; i++) hv[i] = hpT[(k8+i)*BB + b];
        uint4 r4 = *(const uint4*)(wr + k8);
        uint4 z4 = *(const uint4*)(wz + k8);
        uint4 n4 = *(const uint4*)(wn + k8);
        const uint32 ra[4] = {r4.x, r4.y, r4.z, r4.w};
        const uint32 za[4] = {z4.x, z4.y, z4.z, z4.w};
        const uint32 na[4] = {n4.x, n4.y, n4.z, n4.w};
        #pragma unroll
        for (int q = 0; q < 4; q++){
            union { uint32 i; float f; } lo, hi;
            lo.i = ra[q] << 16; hi.i = ra[q] & 0xffff0000u;
            ar += lo.f*hv[2*q] + hi.f*hv[2*q+1];
            lo.i = za[q] << 16; hi.i = za[q] & 0xffff0000u;
            az += lo.f*hv[2*q] + hi.f*hv[2*q+1];
            lo.i = na[q] << 16; hi.i = na[q] & 0xffff0000u;
            an += lo.f*hv[2*q] + hi.f*hv[2*q+1];
        }
    }
    float hj = hpT[j*BB + b];
    const float* girow = gi + b*3072;
    float r = 1.f/(1.f + __expf(-(girow[j]        + ar + bhh[j])));
    float z = 1.f/(1.f + __expf(-(girow[HH + j]   + az + bhh[HH + j])));
    float n = tanhf(girow[2*HH + j] + r*(an + bhh[2*HH + j]));
    float h = (1.f - z)*n + z*hj;
    hnT[j*BB + b] = h;
    hout[b*HH + j] = f2bf(h);
}

// C = A @ B^T + bias.  A: [M][1024] bf16. B: [N][1024] row-major, bf16 (BFP32=0)
// or fp32 (BFP32=1, converted in-register). mode 0: C[row*N+col].
// mode 1: row=(t*32+b) -> C[b*(257*V) + t*V + col] (projection layout).
// Block 256 = 4 waves (2x2 of 64x64 wave tiles) -> 128x128 block tile.
template<int BFP32>
__global__ __launch_bounds__(256) void k_gemm_bt(
    const ushort_t* __restrict__ A, int M,
    const void* __restrict__ Bv, int N,
    const float* __restrict__ bias,
    float* __restrict__ C, int mode)
{
    int wave = threadIdx.x >> 6;
    int lane = threadIdx.x & 63;
    int quad = lane >> 4;
    int l16  = lane & 15;
    int m0 = blockIdx.y*128 + (wave >> 1)*64;
    int n0 = blockIdx.x*128 + (wave & 1)*64;

    const ushort_t* pA[4];
    const ushort_t* pBh[4];
    const float*    pBf[4];
    #pragma unroll
    for (int i = 0; i < 4; i++){
        int r = m0 + i*16 + l16; if (r > M-1) r = M-1;   // clamp: OOB tiles read row M-1, discarded at store
        pA[i] = A + (size_t)r*KK + quad*8;
        int c = n0 + i*16 + l16; if (c > N-1) c = N-1;
        if (BFP32) pBf[i] = (const float*)Bv + (size_t)c*KK + quad*8;
        else       pBh[i] = (const ushort_t*)Bv + (size_t)c*KK + quad*8;
    }
    f32x4 acc[4][4];
    #pragma unroll
    for (int i = 0; i < 4; i++)
        #pragma unroll
        for (int j = 0; j < 4; j++){
            f32x4 z4 = {0.f, 0.f, 0.f, 0.f};
            acc[i][j] = z4;
        }

    for (int kc = 0; kc < KK; kc += 32){
        bf16x8 av[4], bv[4];
        #pragma unroll
        for (int i = 0; i < 4; i++) av[i] = *(const bf16x8*)(pA[i] + kc);
        #pragma unroll
        for (int j = 0; j < 4; j++){
            if (BFP32){
                float4 f0 = *(const float4*)(pBf[j] + kc);
                float4 f1 = *(const float4*)(pBf[j] + kc + 4);
                bf16x8 t;
                t[0]=(short)f2bf(f0.x); t[1]=(short)f2bf(f0.y);
                t[2]=(short)f2bf(f0.z); t[3]=(short)f2bf(f0.w);
                t[4]=(short)f2bf(f1.x); t[5]=(short)f2bf(f1.y);
                t[6]=(short)f2bf(f1.z); t[7]=(short)f2bf(f1.w);
                bv[j] = t;
            } else {
                bv[j] = *(const bf16x8*)(pBh[j] + kc);
            }
        }
        #pragma unroll
        for (int i = 0; i < 4; i++)
            #pragma unroll
            for (int j = 0; j < 4; j++)
                acc[i][j] = __builtin_amdgcn_mfma_f32_16x16x32_bf16(av[i], bv[j], acc[i][j], 0, 0, 0);
    }

    #pragma unroll
    for (int i = 0; i < 4; i++){
        int rbase = m0 + i*16 + quad*4;
        #pragma unroll
        for (int j = 0; j < 4; j++){
            int col = n0 + j*16 + l16;
            if (col >= N) continue;
            float bvv = bias[col];
            #pragma unroll
            for (int rr = 0; rr < 4; rr++){
                int row = rbase + rr;
                if (row >= M) continue;
                float v = acc[i][j][rr] + bvv;
                if (mode == 0) C[(size_t)row*N + col] = v;
                else {
                    int t = row >> 5, b = row & 31;
                    C[(size_t)b*((size_t)U1*VV) + (size_t)t*VV + col] = v;
                }
            }
        }
    }
}

extern "C" void kernel_launch(void* const* d_in, const int* in_sizes, int n_in,
                              void* d_out, int out_size, void* d_ws, size_t ws_size,
                              hipStream_t stream)
{
    const int*   y          = (const int*)  d_in[0];
    const float* embed      = (const float*)d_in[2];
    const float* init_state = (const float*)d_in[3];
    const float* Wih        = (const float*)d_in[4];
    const float* Whh        = (const float*)d_in[5];
    const float* bih        = (const float*)d_in[6];
    const float* bhh        = (const float*)d_in[7];
    const float* Wout       = (const float*)d_in[8];
    const float* bout       = (const float*)d_in[9];
    float* out = (float*)d_out;

    // ---- d_out as scratch (329 MB total; all regions dead before the final
    // projection overwrites d_out) ----
    float* gi0 = out;                              // 101.1 MB (MM*3072 fp32)
    float* gi1 = out + (size_t)MM*3072;            // 101.1 MB
    char*  r2  = (char*)(out + (size_t)2*MM*3072); // 126.9 MB spare
    ushort_t* x0   = (ushort_t*)r2;                      // 16.84 MB
    ushort_t* h0   = (ushort_t*)(r2 + (size_t)MM*HH*2);  // 16.84 MB
    ushort_t* WihB = (ushort_t*)(r2 + (size_t)2*MM*HH*2);            // 12.58 MB
    ushort_t* WhhB = WihB + (size_t)2*3072*1024;                     // 12.58 MB
    // region2 use: 58.85 MB < 126.9 MB available. ok.

    // ---- d_ws: only buffers that must survive the projection ----
    char* w = (char*)d_ws;
    ushort_t* h1  = (ushort_t*)w; w += (size_t)MM*HH*2;   // 16.84 MB
    float*    hTa = (float*)w;    w += (size_t)32768*4;
    float*    hTb = (float*)w;    w += (size_t)32768*4;
    size_t used_b = (size_t)(w - (char*)d_ws);
    size_t need_a = used_b + (size_t)VV*1024*2;           // +20.48 MB for WoutB
    int planA = (ws_size >= need_a) ? 1 : 0;              // constant across calls
    ushort_t* WoutB = (ushort_t*)w;

    k_cast<<<2048, 256, 0, stream>>>(Wih,  WihB,  2*3072*1024);
    k_cast<<<2048, 256, 0, stream>>>(Whh,  WhhB,  2*3072*1024);
    if (planA)
        k_cast<<<2048, 256, 0, stream>>>(Wout, WoutB, VV*1024);
    k_embed<<<4096, 256, 0, stream>>>(y, embed, x0);

    // layer 0: gi0 for all steps, then sequential recurrence
    k_gemm_bt<0><<<dim3(24, 65), 256, 0, stream>>>(x0, MM, WihB, 3072, bih, gi0, 0);
    k_init_hT<<<128, 256, 0, stream>>>(init_state, hTa);
    for (int t = 0; t < U1; t++){
        const float* hp = (t & 1) ? hTb : hTa;
        float*       hn = (t & 1) ? hTa : hTb;
        k_gru_step<<<128, 256, 0, stream>>>(WhhB, bhh, gi0 + (size_t)t*BB*3072,
                                            hp, hn, h0 + (size_t)t*BB*HH);
    }

    // layer 1: gi1 from h0_all, then sequential recurrence
    k_gemm_bt<0><<<dim3(24, 65), 256, 0, stream>>>(h0, MM, WihB + (size_t)3072*1024, 3072,
                                                   bih + 3072, gi1, 0);
    k_init_hT<<<128, 256, 0, stream>>>(init_state + HH, hTa);
    for (int t = 0; t < U1; t++){
        const float* hp = (t & 1) ? hTb : hTa;
        float*       hn = (t & 1) ? hTa : hTb;
        k_gru_step<<<128, 256, 0, stream>>>(WhhB + (size_t)3072*1024, bhh + 3072,
                                            gi1 + (size_t)t*BB*3072,
                                            hp, hn, h1 + (size_t)t*BB*HH);
    }

    // final projection -> all of d_out (reads only d_ws / d_in)
    if (planA)
        k_gemm_bt<0><<<dim3(79, 65), 256, 0, stream>>>(h1, MM, WoutB, VV, bout, out, 1);
    else
        k_gemm_bt<1><<<dim3(79, 65), 256, 0, stream>>>(h1, MM, Wout,  VV, bout, out, 1);
}